// Round 12
// baseline (122.947 us; speedup 1.0000x reference)
//
#include <hip/hip_runtime.h>

typedef unsigned short ushort;
typedef __attribute__((ext_vector_type(4)))  float  f32x4;
typedef __attribute__((ext_vector_type(16))) float  f32x16;
typedef __attribute__((ext_vector_type(8)))  short  s16x8;
typedef __attribute__((ext_vector_type(4)))  ushort u16x4;
typedef __attribute__((ext_vector_type(4)))  unsigned u32x4;

#define MFMA16(a, b, c) __builtin_amdgcn_mfma_f32_16x16x32_bf16((a), (b), (c), 0, 0, 0)
#define MFMA32(a, b, c) __builtin_amdgcn_mfma_f32_32x32x16_bf16((a), (b), (c), 0, 0, 0)

__device__ __forceinline__ ushort f2bf(float f) {
    unsigned u = __builtin_bit_cast(unsigned, f);
    u = (u + 0x7FFF + ((u >> 16) & 1)) >> 16;   // RNE
    return (ushort)u;
}

__device__ __forceinline__ unsigned cvtpk_bf16(float lo, float hi) {
    unsigned r;
    asm("v_cvt_pk_bf16_f32 %0, %1, %2" : "=v"(r) : "v"(lo), "v"(hi));
    return r;
}
// After the swap: a = [a_lo31 | b_lo31], b = [a_hi31 | b_hi31].
// Only safe when a and b are DISTINCT SSA values (regalloc coalescing hazard).
__device__ __forceinline__ void plswap(unsigned& a, unsigned& b) {
    asm volatile("v_permlane32_swap_b32 %0, %1" : "+v"(a), "+v"(b));
}
// Pair (lane ^ 32) max via permlane32_swap (pure VALU, no DS op). The v_mov
// through asm forces b into a distinct physreg (coalescing hazard).
__device__ __forceinline__ float pairmax(float x) {
    unsigned a = __builtin_bit_cast(unsigned, x), b;
    asm("v_mov_b32 %0, %1" : "=v"(b) : "v"(a));
    plswap(a, b);
    return fmaxf(__builtin_bit_cast(float, a), __builtin_bit_cast(float, b));
}
// Raw 2^x. exp() folded to exp2 via Q pre-scale by log2(e).
__device__ __forceinline__ float fast_exp2(float x) {
    float r;
    asm("v_exp_f32 %0, %1" : "=v"(r) : "v"(x));
    return r;
}

__device__ __forceinline__ void gload_lds16(const ushort* g, ushort* l) {
    __builtin_amdgcn_global_load_lds(
        (const __attribute__((address_space(1))) void*)g,
        (__attribute__((address_space(3))) void*)l, 16, 0, 0);
}

// ---------------------------------------------------------------------------
// fp32 -> bf16 conversion for all three inputs in ONE dispatch.
// ---------------------------------------------------------------------------
__global__ __launch_bounds__(256) void cvt_all(
    const float* __restrict__ x, const float* __restrict__ wq,
    const float* __restrict__ wp, ushort* __restrict__ out,
    int n4x, int n4q, int n4p)
{
    int i = blockIdx.x * blockDim.x + threadIdx.x;
    const int stride = gridDim.x * blockDim.x;
    const int total = n4x + n4q + n4p;
    for (; i < total; i += stride) {
        float4 v;
        if (i < n4x)            v = ((const float4*)x)[i];
        else if (i < n4x + n4q) v = ((const float4*)wq)[i - n4x];
        else                    v = ((const float4*)wp)[i - n4x - n4q];
        u16x4 o;
        o[0] = f2bf(v.x); o[1] = f2bf(v.y); o[2] = f2bf(v.z); o[3] = f2bf(v.w);
        ((u16x4*)out)[i] = o;
    }
}

// ---------------------------------------------------------------------------
// 128x128 tile GEMM mainloop, 3-buffer / 2-deep prefetch / counted vmcnt,
// slot-XOR bank swizzle. Unchanged from R11.
// ---------------------------------------------------------------------------
__device__ __forceinline__ void gemm128_mainloop(
    const ushort* __restrict__ A, const ushort* __restrict__ B, int K,
    int row0, int col0, ushort* As, ushort* Bs, f32x4 acc[4][4])
{
    const int t  = threadIdx.x;
    const int l  = t & 63;
    const int w  = t >> 6;
    const int lr = l & 15, lg = l >> 4;
    const int wm = w >> 1, wn = w & 1;

#pragma unroll
    for (int m = 0; m < 4; m++)
#pragma unroll
        for (int n = 0; n < 4; n++) acc[m][n] = (f32x4){0.f, 0.f, 0.f, 0.f};

    const int slot = (t & 3) ^ ((t >> 3) & 3);
    const ushort* ga0 = A + (row0 + (t >> 2)) * K + slot * 8;
    const ushort* gb0 = B + (col0 + (t >> 2)) * K + slot * 8;
    const int rowsz = 64 * K;
    ushort* la0 = As + t * 8;
    ushort* lb0 = Bs + t * 8;

    auto STAGE = [&](int kt, int buf) {
        const int k0  = kt * 32;
        const int off = buf * 4096;
        gload_lds16(ga0 + k0,         la0 + off);
        gload_lds16(ga0 + rowsz + k0, la0 + off + 2048);
        gload_lds16(gb0 + k0,         lb0 + off);
        gload_lds16(gb0 + rowsz + k0, lb0 + off + 2048);
    };
    const int sx = (lg ^ ((lr >> 1) & 3)) * 8;
    auto COMPUTE = [&](int buf) {
        const ushort* Ab = As + buf * 4096;
        const ushort* Bb = Bs + buf * 4096;
        s16x8 af[4], bfr[4];
#pragma unroll
        for (int m = 0; m < 4; m++)
            af[m] = *(const s16x8*)&Ab[(wm * 64 + m * 16 + lr) * 32 + sx];
#pragma unroll
        for (int n = 0; n < 4; n++)
            bfr[n] = *(const s16x8*)&Bb[(wn * 64 + n * 16 + lr) * 32 + sx];
        __builtin_amdgcn_s_setprio(1);
#pragma unroll
        for (int m = 0; m < 4; m++)
#pragma unroll
            for (int n = 0; n < 4; n++)
                acc[m][n] = MFMA16(af[m], bfr[n], acc[m][n]);
        __builtin_amdgcn_s_setprio(0);
    };

    const int nt = K >> 5;          // 24; must be divisible by 3
    STAGE(0, 0);
    STAGE(1, 1);
    asm volatile("s_waitcnt vmcnt(4)" ::: "memory");
    __builtin_amdgcn_s_barrier();

#define GSTEP(IT, CBUF, SBUF)                                          \
    {                                                                  \
        const int sk = (IT) + 2;                                       \
        const bool st = sk < nt;                                       \
        if (st) STAGE(sk, SBUF);                                       \
        COMPUTE(CBUF);                                                 \
        if (st) { asm volatile("s_waitcnt vmcnt(4)" ::: "memory"); }   \
        else    { asm volatile("s_waitcnt vmcnt(0)" ::: "memory"); }   \
        __builtin_amdgcn_s_barrier();                                  \
    }

    for (int base = 0; base < nt; base += 3) {
        GSTEP(base,     0, 2);
        GSTEP(base + 1, 1, 0);
        GSTEP(base + 2, 2, 1);
    }
#undef GSTEP
}

// ---------------------------------------------------------------------------
// Kernel 1: QKV = x @ qkv_w^T, scatter into q[bh][n][64] (pre-scaled by
// SCALE*log2e), k[bh][n][64], vT[bh][64][n].  grid (64, 18), block 256.
// ---------------------------------------------------------------------------
__global__ __launch_bounds__(256) void qkv_gemm(
    const ushort* __restrict__ X, const ushort* __restrict__ W,
    ushort* __restrict__ qb, ushort* __restrict__ kb, ushort* __restrict__ vb)
{
    __shared__ __align__(16) ushort As[3 * 128 * 32];
    __shared__ __align__(16) ushort Bs[3 * 128 * 32];
    f32x4 acc[4][4];
    const int br = blockIdx.x, bc = blockIdx.y;
    gemm128_mainloop(X, W, 768, br * 128, bc * 128, As, Bs, acc);

    const int t = threadIdx.x, l = t & 63, w = t >> 6;
    const int lr = l & 15, lg = l >> 4, wm = w >> 1, wn = w & 1;
    const int p = (bc * 128) / 768;
    const int mrow0 = br * 128 + wm * 64 + lg * 4;
    const int ecolB = bc * 128 + wn * 64 + lr;
    const float QSCALE = 0.125f * 1.44269504088896f;  // SCALE * log2(e)

#pragma unroll
    for (int n = 0; n < 4; n++) {
        const int e   = ecolB + n * 16;
        const int rem = e - p * 768;
        const int h   = rem >> 6;
        const int hd  = rem & 63;
#pragma unroll
        for (int m = 0; m < 4; m++) {
            const int mr = mrow0 + m * 16;
            const int b  = mr >> 10;
            const int nn = mr & 1023;
            const f32x4 v = acc[m][n];
            const int bh = b * 12 + h;
            if (p == 0) {
                ushort* dst = qb + (bh * 1024 + nn) * 64 + hd;
#pragma unroll
                for (int r = 0; r < 4; r++) dst[r * 64] = f2bf(v[r] * QSCALE);
            } else if (p == 1) {
                ushort* dst = kb + (bh * 1024 + nn) * 64 + hd;
#pragma unroll
                for (int r = 0; r < 4; r++) dst[r * 64] = f2bf(v[r]);
            } else {
                u16x4 pk;
                pk[0] = f2bf(v[0]); pk[1] = f2bf(v[1]);
                pk[2] = f2bf(v[2]); pk[3] = f2bf(v[3]);
                *(u16x4*)(vb + (bh * 64 + hd) * 1024 + nn) = pk;
            }
        }
    }
}

// ---------------------------------------------------------------------------
// Kernel 2: flash attention, 32x32 swapped-QK, KVBLK=64 (two 32-kv sub-tiles
// sharing one softmax pass — R5's verified math, fed from LDS).
// K/V staged via 3-buffer / 2-deep prefetch / vmcnt(4) (GEMM-proven schedule).
// LDS per buf: K[64 rows][128B] (row=kv, 64 d) | V[64 rows][128B] (row=d,
// 64 kv), both with slot involution p ^= (row&7) on source and read.
// lsum accumulated via mfma32(ones, P^T) -> ls[0]; rescale touches ls[0] only.
// grid (96 bh, 8 qt), block 256 = 4 waves; 16 kv-iterations.
// ---------------------------------------------------------------------------
__global__ __launch_bounds__(256) void attn_kernel(
    const ushort* __restrict__ qb, const ushort* __restrict__ kb,
    const ushort* __restrict__ vb, ushort* __restrict__ ao)
{
    __shared__ __align__(16) ushort KV[3][8192];   // [buf][K 4096 | V 4096] = 48KB
    const int bh = blockIdx.x, qt = blockIdx.y;
    const int b = bh / 12, h = bh - b * 12;
    const int t = threadIdx.x, l = t & 63, w = t >> 6;
    const int lq = l & 31, hi = l >> 5;
    const int qr0 = qt * 128 + w * 32;

    // ---- staging sources (pre-swizzled): per gload thread t fills LDS row
    //      t>>3, 16B-slot t&7; source slot = (t&7) ^ ((t>>3)&7).
    const int srow = t >> 3;                        // 0..31
    const int ss   = (t & 7) ^ (srow & 7);
    const ushort* ksrc = kb + (size_t)(bh * 1024 + srow) * 64 + ss * 8;   // +kt*4096
    const ushort* vsrc = vb + (size_t)(bh * 64 + srow) * 1024 + ss * 8;   // +kt*64
    ushort* kdst = &KV[0][0]    + t * 8;            // uniform base + lane*16B
    ushort* vdst = &KV[0][4096] + t * 8;

    auto STAGE = [&](int kt, int buf) {
        const ushort* ks = ksrc + kt * 4096;
        const ushort* vs = vsrc + kt * 64;
        ushort* kd = kdst + buf * 8192;
        ushort* vd = vdst + buf * 8192;
        gload_lds16(ks,             kd);            // K rows 0-31
        gload_lds16(ks + 2048,      kd + 2048);     // K rows 32-63
        gload_lds16(vs,             vd);            // V d 0-31
        gload_lds16(vs + 32 * 1024, vd + 2048);     // V d 32-63
    };

    // ---- Q fragments (B-operand): col=q=lq, k=d-slice s*16 + hi*8 ----
    const ushort* qlane = qb + (bh * 1024 + qr0 + lq) * 64 + hi * 8;
    s16x8 qf[4];
#pragma unroll
    for (int s = 0; s < 4; s++) qf[s] = *(const s16x8*)(qlane + s * 16);

    // ones fragment (bf16 1.0 x8) for the lsum MFMA
    const unsigned one2 = 0x3F803F80u;
    const u32x4 onev = {one2, one2, one2, one2};
    const s16x8 onesf = __builtin_bit_cast(s16x8, onev);

    float m = -__builtin_inff();
    f32x16 o0 = {}, o1 = {}, ls = {};

    // prologue: tiles 0,1 in flight
    STAGE(0, 0);
    STAGE(1, 1);
    asm volatile("s_waitcnt vmcnt(4)" ::: "memory");   // tile0 landed
    __builtin_amdgcn_s_barrier();

    const int fx = (lq & 7) << 4;                   // read-side swizzle
    int cur = 0;
    for (int it = 0; it < 16; ++it) {
        // ---- prefetch tile it+2 into buffer (it+2)%3 ----
        const bool st = it < 14;
        if (st) {
            int sbuf = cur + 2; if (sbuf >= 3) sbuf -= 3;
            STAGE(it + 2, sbuf);
        }
        const char* Kb = (const char*)&KV[cur][0];
        const char* Vb = (const char*)&KV[cur][4096];

        // ---- K fragments: sub-tile A rows lq, sub-tile B rows 32+lq ----
        s16x8 kfA[4], kfB[4];
#pragma unroll
        for (int s = 0; s < 4; s++) {
            kfA[s] = *(const s16x8*)(Kb + lq * 128        + ((hi * 16 + s * 32) ^ fx));
            kfB[s] = *(const s16x8*)(Kb + (32 + lq) * 128 + ((hi * 16 + s * 32) ^ fx));
        }

        f32x16 sa = {}, sb = {};
        __builtin_amdgcn_s_setprio(1);
#pragma unroll
        for (int s = 0; s < 4; s++) {
            sa = MFMA32(kfA[s], qf[s], sa);
            sb = MFMA32(kfB[s], qf[s], sb);
        }
        __builtin_amdgcn_s_setprio(0);

        // ---- joint online softmax over 64 kv (32/lane, pair has rest) ----
        float tm[8];
#pragma unroll
        for (int r = 0; r < 8; r++)
            tm[r] = fmaxf(fmaxf(sa[r], sa[r + 8]), fmaxf(sb[r], sb[r + 8]));
        float u0 = fmaxf(fmaxf(tm[0], tm[1]), fmaxf(tm[2], tm[3]));
        float u1 = fmaxf(fmaxf(tm[4], tm[5]), fmaxf(tm[6], tm[7]));
        const float mx = pairmax(fmaxf(u0, u1));

        if (!__all(mx <= m + 8.f)) {          // defer-max (T13), log2 units
            const float mn = fmaxf(m, mx);
            const float fac = fast_exp2(m - mn);  // first iter: exp2(-inf)=0
            m = mn;
            ls[0] *= fac;
#pragma unroll
            for (int r = 0; r < 16; r++) { o0[r] *= fac; o1[r] *= fac; }
        }

        // ---- P = exp2(S - m); pack P^T fragments (cvt_pk + permlane) ----
        s16x8 pfA[2], pfB[2];
        {
            float pa[16];
#pragma unroll
            for (int r = 0; r < 16; r++) pa[r] = fast_exp2(sa[r] - m);
#pragma unroll
            for (int slot = 0; slot < 2; slot++) {
                const int r0 = slot * 8;
                unsigned a0 = cvtpk_bf16(pa[r0 + 0], pa[r0 + 1]);
                unsigned a1 = cvtpk_bf16(pa[r0 + 4], pa[r0 + 5]);
                plswap(a0, a1);
                unsigned b0 = cvtpk_bf16(pa[r0 + 2], pa[r0 + 3]);
                unsigned b1 = cvtpk_bf16(pa[r0 + 6], pa[r0 + 7]);
                plswap(b0, b1);
                const u32x4 u = {a0, b0, a1, b1};
                pfA[slot] = __builtin_bit_cast(s16x8, u);
            }
        }
        {
            float pb[16];
#pragma unroll
            for (int r = 0; r < 16; r++) pb[r] = fast_exp2(sb[r] - m);
#pragma unroll
            for (int slot = 0; slot < 2; slot++) {
                const int r0 = slot * 8;
                unsigned a0 = cvtpk_bf16(pb[r0 + 0], pb[r0 + 1]);
                unsigned a1 = cvtpk_bf16(pb[r0 + 4], pb[r0 + 5]);
                plswap(a0, a1);
                unsigned b0 = cvtpk_bf16(pb[r0 + 2], pb[r0 + 3]);
                unsigned b1 = cvtpk_bf16(pb[r0 + 6], pb[r0 + 7]);
                plswap(b0, b1);
                const u32x4 u = {a0, b0, a1, b1};
                pfB[slot] = __builtin_bit_cast(s16x8, u);
            }
        }

        // ---- V fragments + PV + lsum MFMA ----
        s16x8 vA[2][2], vB[2][2];   // [half d0/d32][k-slot]
#pragma unroll
        for (int half = 0; half < 2; half++)
#pragma unroll
            for (int s = 0; s < 2; s++) {
                const int rowb = (32 * half + lq) * 128;
                vA[half][s] = *(const s16x8*)(Vb + rowb + ((s * 32 + hi * 16) ^ fx));
                vB[half][s] = *(const s16x8*)(Vb + rowb + ((64 + s * 32 + hi * 16) ^ fx));
            }
        __builtin_amdgcn_s_setprio(1);
        o0 = MFMA32(vA[0][0], pfA[0], o0);
        o1 = MFMA32(vA[1][0], pfA[0], o1);
        o0 = MFMA32(vA[0][1], pfA[1], o0);
        o1 = MFMA32(vA[1][1], pfA[1], o1);
        o0 = MFMA32(vB[0][0], pfB[0], o0);
        o1 = MFMA32(vB[1][0], pfB[0], o1);
        o0 = MFMA32(vB[0][1], pfB[1], o0);
        o1 = MFMA32(vB[1][1], pfB[1], o1);
        ls = MFMA32(onesf, pfA[0], ls);
        ls = MFMA32(onesf, pfA[1], ls);
        ls = MFMA32(onesf, pfB[0], ls);
        ls = MFMA32(onesf, pfB[1], ls);
        __builtin_amdgcn_s_setprio(0);

        if (st) { asm volatile("s_waitcnt vmcnt(4)" ::: "memory"); }
        else    { asm volatile("s_waitcnt vmcnt(0)" ::: "memory"); }
        __builtin_amdgcn_s_barrier();
        cur = (cur == 2) ? 0 : cur + 1;
    }

    // ---- epilogue: out[b][q][h*64+d] = O^T[d][q] / lsum ----
    const float inv = 1.f / ls[0];
    ushort* op = ao + (b * 1024 + qr0 + lq) * 768 + h * 64 + 4 * hi;
#pragma unroll
    for (int i = 0; i < 4; i++) {
        u16x4 pk0, pk1;
#pragma unroll
        for (int j = 0; j < 4; j++) {
            pk0[j] = f2bf(o0[4 * i + j] * inv);
            pk1[j] = f2bf(o1[4 * i + j] * inv);
        }
        *(u16x4*)(op + 8 * i)      = pk0;   // d = 8i+4hi + 0..3
        *(u16x4*)(op + 32 + 8 * i) = pk1;   // d = 32 + 8i+4hi + 0..3
    }
}

// ---------------------------------------------------------------------------
// Kernel 3: out = attn_out @ proj_w^T + proj_b (fp32 out). grid (64, 6).
// ---------------------------------------------------------------------------
__global__ __launch_bounds__(256) void proj_gemm(
    const ushort* __restrict__ A, const ushort* __restrict__ W,
    const float* __restrict__ bias, float* __restrict__ out)
{
    __shared__ __align__(16) ushort As[3 * 128 * 32];
    __shared__ __align__(16) ushort Bs[3 * 128 * 32];
    f32x4 acc[4][4];
    const int br = blockIdx.x, bc = blockIdx.y;
    gemm128_mainloop(A, W, 768, br * 128, bc * 128, As, Bs, acc);

    const int t = threadIdx.x, l = t & 63, w = t >> 6;
    const int lr = l & 15, lg = l >> 4, wm = w >> 1, wn = w & 1;
    const int mrow0 = br * 128 + wm * 64 + lg * 4;
    const int ecolB = bc * 128 + wn * 64 + lr;

#pragma unroll
    for (int n = 0; n < 4; n++) {
        const int e = ecolB + n * 16;
        const float bv = bias[e];
#pragma unroll
        for (int m = 0; m < 4; m++) {
            const int mr = mrow0 + m * 16;
#pragma unroll
            for (int r = 0; r < 4; r++)
                out[(mr + r) * 768 + e] = acc[m][n][r] + bv;
        }
    }
}

// ---------------------------------------------------------------------------
extern "C" void kernel_launch(void* const* d_in, const int* in_sizes, int n_in,
                              void* d_out, int out_size, void* d_ws, size_t ws_size,
                              hipStream_t stream)
{
    const float* x  = (const float*)d_in[0];   // [8,1024,768] f32
    const float* wq = (const float*)d_in[1];   // [2304,768]   f32
    const float* wp = (const float*)d_in[2];   // [768,768]    f32
    const float* pb = (const float*)d_in[3];   // [768]        f32
    float* out = (float*)d_out;                // [8,1024,768] f32

    const int NX = 8 * 1024 * 768;             // 6291456
    const int NQ = 2304 * 768;                 // 1769472
    const int NP = 768 * 768;                  // 589824
    const int SEG = 8 * 12 * 1024 * 64;        // 6291456

    ushort* xb  = (ushort*)d_ws;               // x bf16; reused as ao after qkv
    ushort* wqb = xb + NX;
    ushort* wpb = wqb + NQ;
    ushort* qb  = wpb + NP;                    // q  [bh][n][64]  (pre-scaled)
    ushort* kb  = qb + SEG;                    // k  [bh][n][64]
    ushort* vb  = kb + SEG;                    // vT [bh][64][n]
    ushort* ao  = xb;                          // attn out aliases xb (dead by then)

    cvt_all<<<2048, 256, 0, stream>>>(x, wq, wp, xb, NX / 4, NQ / 4, NP / 4);

    qkv_gemm  <<<dim3(64, 18), 256, 0, stream>>>(xb, wqb, qb, kb, vb);
    attn_kernel<<<dim3(96, 8), 256, 0, stream>>>(qb, kb, vb, ao);
    proj_gemm <<<dim3(64, 6), 256, 0, stream>>>(ao, wpb, pb, out);
}